// Round 1
// baseline (1017.715 us; speedup 1.0000x reference)
//
#include <hip/hip_runtime.h>

// KmeansAttention: b=2 h=8 t=8192 d=64 c=64 wsz=128
// inputs: qk[b,h,t,d] f32, v[b,h,t,d] f32, means[h,c,d] f32 (pre-normalized),
//         rel_weights[128,h,64] f32.  output: f32 [b,h,t,d]
//
// Pipeline: A) routing dists as sortable keys (f64 accumulate for exact ranking)
//           B) per-(b,h,c) radix-select top-128 tokens, ascending indices
//           C) per-window 128x128 attention (Gram + rel-shift + softmax + PV),
//              atomic scatter into numer(d_out) + count
//           D) out = numer / (count + 1e-5)

#define TOKEN_SELF -50000.0f

// ---------------- Kernel A: routing distances -> sortable keys ----------------
template <typename KeyT>
__global__ __launch_bounds__(256) void dists_kernel(const float* __restrict__ qk,
                                                    const float* __restrict__ means,
                                                    KeyT* __restrict__ keys) {
    __shared__ double ms[4096];              // means[h] as f64, 32KB
    const int tid = threadIdx.x;
    const int bh = blockIdx.x >> 5;          // [0,16)
    const int tc = blockIdx.x & 31;          // token chunk of 256
    const int h = bh & 7;
    for (int k = tid; k < 4096; k += 256) ms[k] = (double)means[h * 4096 + k];
    __syncthreads();
    const int t = (tc << 8) + tid;
    const float4* row = reinterpret_cast<const float4*>(qk + (((size_t)bh << 13) + t) * 64);
    double x[64];
#pragma unroll
    for (int k = 0; k < 16; ++k) {
        float4 f = row[k];
        x[4*k+0] = f.x; x[4*k+1] = f.y; x[4*k+2] = f.z; x[4*k+3] = f.w;
    }
    double n2 = 0.0;
#pragma unroll
    for (int d = 0; d < 64; ++d) n2 += x[d] * x[d];
    double den = sqrt(n2);
    den = den > 1e-12 ? den : 1e-12;
    const double rden = 1.0 / den;
    KeyT* dst = keys + ((size_t)bh << 19) + t;     // [bh][c][t]
    for (int c = 0; c < 64; ++c) {
        double acc = 0.0;
#pragma unroll
        for (int d = 0; d < 64; ++d) acc += x[d] * ms[(c << 6) + d];
        const double val = acc * rden;
        KeyT key;
        if constexpr (sizeof(KeyT) == 8) {
            unsigned long long u = (unsigned long long)__double_as_longlong(val);
            key = (KeyT)((u & 0x8000000000000000ULL) ? ~u : (u | 0x8000000000000000ULL));
        } else {
            unsigned u = __float_as_uint((float)val);
            key = (KeyT)((u & 0x80000000u) ? ~u : (u | 0x80000000u));
        }
        dst[(size_t)c << 13] = key;
    }
}

// ---------------- Kernel B: exact top-128 per (b,h,c), ascending ----------------
template <typename KeyT>
__global__ __launch_bounds__(256) void topk_kernel(const KeyT* __restrict__ keys,
                                                   int* __restrict__ idx_out) {
    __shared__ KeyT key[8192];
    __shared__ unsigned hist[256];
    __shared__ unsigned sgt[256], seq[256];
    __shared__ KeyT s_prefix;
    __shared__ unsigned s_need;
    const int tid = threadIdx.x;
    const KeyT* col = keys + ((size_t)blockIdx.x << 13);
    for (int k = tid; k < 8192; k += 256) key[k] = col[k];
    if (tid == 0) { s_prefix = (KeyT)0; s_need = 128u; }
    __syncthreads();
    constexpr int NBITS = (int)sizeof(KeyT) * 8;
    KeyT prefix = (KeyT)0;
    for (int shift = NBITS - 8; shift >= 0; shift -= 8) {
        hist[tid] = 0u;
        __syncthreads();
        const KeyT maskHi = (shift == NBITS - 8) ? (KeyT)0 : (KeyT)((~(KeyT)0) << (shift + 8));
        for (int k = tid; k < 8192; k += 256) {
            KeyT u = key[k];
            if ((u & maskHi) == prefix) atomicAdd(&hist[(unsigned)(u >> shift) & 255u], 1u);
        }
        __syncthreads();
        if (tid == 0) {
            unsigned needL = s_need, acc = 0;
            int dsel = 0;
            for (int d = 255; d >= 0; --d) {
                unsigned c = hist[d];
                if (acc + c >= needL) { dsel = d; s_need = needL - acc; break; }
                acc += c;
            }
            s_prefix = (KeyT)(s_prefix | ((KeyT)dsel << shift));
        }
        __syncthreads();
        prefix = s_prefix;
    }
    const KeyT V = prefix;
    const unsigned rneed = s_need;
    const int base = tid << 5;
    unsigned cgt = 0, ceq = 0;
    for (int k = 0; k < 32; ++k) {
        KeyT u = key[base + k];
        cgt += (u > V) ? 1u : 0u;
        ceq += (u == V) ? 1u : 0u;
    }
    sgt[tid] = cgt; seq[tid] = ceq;
    __syncthreads();
    for (int off = 1; off < 256; off <<= 1) {
        unsigned ag = (tid >= off) ? sgt[tid - off] : 0u;
        unsigned ae = (tid >= off) ? seq[tid - off] : 0u;
        __syncthreads();
        sgt[tid] += ag; seq[tid] += ae;
        __syncthreads();
    }
    unsigned g = sgt[tid] - cgt;
    unsigned e = seq[tid] - ceq;
    int* out = idx_out + (blockIdx.x << 7);
    for (int k = 0; k < 32; ++k) {
        KeyT u = key[base + k];
        if (u > V) {
            out[g + (e < rneed ? e : rneed)] = base + k;
            ++g;
        } else if (u == V) {
            if (e < rneed) out[g + e] = base + k;
            ++e;
        }
    }
}

// ---------------- Kernel C: windowed attention + scatter ----------------
__global__ __launch_bounds__(256) void attn_kernel(const float* __restrict__ qk,
                                                   const float* __restrict__ vv,
                                                   const float* __restrict__ relw,
                                                   const int* __restrict__ idx,
                                                   float* __restrict__ numer,
                                                   float* __restrict__ dcnt) {
    __shared__ float qs[128 * 68];        // gathered q rows, stride 68 (16B aligned)
    __shared__ float rv[128 * 68];        // rel_weights rows, later v rows
    __shared__ float dots[128 * 129];     // logits -> probs
    __shared__ float invn[128];           // 1/||q|| then 1/sum
    __shared__ int idxs[128];
    const int tid = threadIdx.x;
    const int bh = blockIdx.x >> 6;
    const int h = bh & 7;
    const float scale = 0.125f;           // d^-0.5

    if (tid < 128) { idxs[tid] = idx[(blockIdx.x << 7) + tid]; invn[tid] = 0.f; }
    __syncthreads();

    const int r = tid >> 1, half = tid & 1;
    {
        const float4* src = reinterpret_cast<const float4*>(
            qk + (((size_t)bh << 13) + idxs[r]) * 64 + half * 32);
        float4* dq = reinterpret_cast<float4*>(&qs[r * 68 + half * 32]);
        float nrm = 0.f;
#pragma unroll
        for (int k = 0; k < 8; ++k) {
            float4 f = src[k];
            dq[k] = f;
            nrm += f.x * f.x + f.y * f.y + f.z * f.z + f.w * f.w;
        }
        atomicAdd(&invn[r], nrm);
        const float4* srw = reinterpret_cast<const float4*>(relw + ((r << 3) + h) * 64 + half * 32);
        float4* drw = reinterpret_cast<float4*>(&rv[r * 68 + half * 32]);
#pragma unroll
        for (int k = 0; k < 8; ++k) drw[k] = srw[k];
    }
    __syncthreads();
    if (tid < 128) invn[tid] = 1.0f / fmaxf(sqrtf(invn[tid]), 1e-12f);
    __syncthreads();

    const int i = tid & 127;
    float qreg[64];
#pragma unroll
    for (int k = 0; k < 16; ++k) {
        float4 f = reinterpret_cast<const float4*>(&qs[i * 68])[k];
        qreg[4*k] = f.x; qreg[4*k+1] = f.y; qreg[4*k+2] = f.z; qreg[4*k+3] = f.w;
    }
    // ---- dots = scale * inv[j] * (q_i . q_j), diagonal = TOKEN_SELF ----
    {
        const int j0 = (tid >> 7) << 6;
        for (int j = j0; j < j0 + 64; ++j) {
            float s = 0.f;
            const float4* qj = reinterpret_cast<const float4*>(&qs[j * 68]);
#pragma unroll
            for (int k = 0; k < 16; ++k) {
                float4 f = qj[k];
                s += qreg[4*k] * f.x + qreg[4*k+1] * f.y + qreg[4*k+2] * f.z + qreg[4*k+3] * f.w;
            }
            dots[i * 129 + j] = (j == i) ? TOKEN_SELF : s * scale * invn[j];
        }
    }
    __syncthreads();
    // ---- rel: dots[i][j] += scale * (q_i . relw[127 + j - i]) for j <= i ----
    {
        const int o0 = (tid >> 7) << 6;
        for (int o = o0; o < o0 + 64; ++o) {
            const int j = i + o - 127;
            if (j >= 0 && j != i) {
                float s = 0.f;
                const float4* rw = reinterpret_cast<const float4*>(&rv[o * 68]);
#pragma unroll
                for (int k = 0; k < 16; ++k) {
                    float4 f = rw[k];
                    s += qreg[4*k] * f.x + qreg[4*k+1] * f.y + qreg[4*k+2] * f.z + qreg[4*k+3] * f.w;
                }
                dots[i * 129 + j] += s * scale;
            }
        }
    }
    __syncthreads();
    // ---- load v (overwrite rv) + softmax ----
    {
        const float4* sv = reinterpret_cast<const float4*>(
            vv + (((size_t)bh << 13) + idxs[r]) * 64 + half * 32);
        float4* dv = reinterpret_cast<float4*>(&rv[r * 68 + half * 32]);
#pragma unroll
        for (int k = 0; k < 8; ++k) dv[k] = sv[k];
    }
    if (tid < 128) {
        float m = -1e30f;
        for (int j = 0; j < 128; ++j) m = fmaxf(m, dots[tid * 129 + j]);
        float ssum = 0.f;
        for (int j = 0; j < 128; ++j) {
            float p = __expf(dots[tid * 129 + j] - m);
            dots[tid * 129 + j] = p;
            ssum += p;
        }
        invn[tid] = 1.0f / ssum;
    }
    __syncthreads();
    // ---- PV + scatter ----
    const int dhalf = tid >> 7;
    float acc[32];
#pragma unroll
    for (int k = 0; k < 32; ++k) acc[k] = 0.f;
    for (int j = 0; j < 128; ++j) {
        const float pj = dots[i * 129 + j];
        const float4* v4 = reinterpret_cast<const float4*>(&rv[j * 68 + dhalf * 32]);
#pragma unroll
        for (int k = 0; k < 8; ++k) {
            float4 f = v4[k];
            acc[4*k]   += pj * f.x;
            acc[4*k+1] += pj * f.y;
            acc[4*k+2] += pj * f.z;
            acc[4*k+3] += pj * f.w;
        }
    }
    const float rs = invn[i];
    const int tok = idxs[i];
    float* dst = numer + (((size_t)bh << 13) + tok) * 64 + dhalf * 32;
#pragma unroll
    for (int k = 0; k < 32; ++k) atomicAdd(&dst[k], acc[k] * rs);
    if (tid < 128) atomicAdd(&dcnt[(bh << 13) + idxs[tid]], 1.0f);
}

// ---------------- Kernel D: finalize ----------------
__global__ __launch_bounds__(256) void finalize_kernel(float4* __restrict__ out,
                                                       const float* __restrict__ dcnt) {
    const int i = blockIdx.x * 256 + threadIdx.x;   // [0, 2097152)
    const float dnm = dcnt[i >> 4] + 1e-5f;
    float4 o = out[i];
    o.x /= dnm; o.y /= dnm; o.z /= dnm; o.w /= dnm;
    out[i] = o;
}

extern "C" void kernel_launch(void* const* d_in, const int* in_sizes, int n_in,
                              void* d_out, int out_size, void* d_ws, size_t ws_size,
                              hipStream_t stream) {
    const float* qk    = (const float*)d_in[0];
    const float* vv    = (const float*)d_in[1];
    const float* means = (const float*)d_in[2];
    const float* relw  = (const float*)d_in[3];
    float* out = (float*)d_out;

    const size_t nkeys     = (size_t)16 * 64 * 8192;   // 8,388,608 keys
    const size_t idx_bytes = (size_t)1024 * 128 * 4;   // 524,288
    const size_t cnt_bytes = (size_t)16 * 8192 * 4;    // 524,288
    const bool big = ws_size >= nkeys * 8 + idx_bytes + cnt_bytes;
    char* wsb = (char*)d_ws;
    const size_t keyBytes = big ? nkeys * 8 : nkeys * 4;
    int* idxp   = (int*)(wsb + keyBytes);
    float* dcnt = (float*)(wsb + keyBytes + idx_bytes);

    hipMemsetAsync(d_out, 0, (size_t)out_size * 4, stream);
    hipMemsetAsync(dcnt, 0, cnt_bytes, stream);

    if (big) {
        dists_kernel<unsigned long long><<<512, 256, 0, stream>>>(qk, means, (unsigned long long*)wsb);
        topk_kernel<unsigned long long><<<1024, 256, 0, stream>>>((const unsigned long long*)wsb, idxp);
    } else {
        dists_kernel<unsigned><<<512, 256, 0, stream>>>(qk, means, (unsigned*)wsb);
        topk_kernel<unsigned><<<1024, 256, 0, stream>>>((const unsigned*)wsb, idxp);
    }
    attn_kernel<<<1024, 256, 0, stream>>>(qk, vv, relw, idxp, out, dcnt);
    finalize_kernel<<<8192, 256, 0, stream>>>((float4*)d_out, dcnt);
}

// Round 2
// 233.117 us; speedup vs baseline: 4.3657x; 4.3657x over previous
//
#include <hip/hip_runtime.h>

// KmeansAttention: b=2 h=8 t=8192 d=64 c=64 wsz=128
// A) routing dists -> sortable u64 keys (f64 accumulate, exact ranking)
// B) per-(b,h,c) radix-select top-128 tokens, ascending indices
// C) per-window 128x128 MFMA attention (split-bf16 Gram + rel-shift + softmax
//    + split-bf16 PV), atomic scatter into numer(d_out) + count
// D) out = numer / (count + 1e-5)

#define TOKEN_SELF -50000.0f

typedef __attribute__((ext_vector_type(8))) short short8;
typedef __attribute__((ext_vector_type(4))) float f32x4;

__device__ __forceinline__ unsigned short f2bf(float x) {
    unsigned u = __float_as_uint(x);
    u += 0x7fffu + ((u >> 16) & 1u);
    return (unsigned short)(u >> 16);
}
__device__ __forceinline__ float bf2f(unsigned short b) {
    return __uint_as_float(((unsigned)b) << 16);
}

// ---------------- Kernel A: routing distances -> sortable keys ----------------
__global__ __launch_bounds__(256) void dists_kernel(const float* __restrict__ qk,
                                                    const float* __restrict__ means,
                                                    unsigned long long* __restrict__ keys) {
    __shared__ double ms[4096];              // means[h] as f64, 32KB
    const int tid = threadIdx.x;
    const int bh = blockIdx.x >> 5;          // [0,16)
    const int tc = blockIdx.x & 31;          // token chunk of 256
    const int h = bh & 7;
    for (int k = tid; k < 4096; k += 256) ms[k] = (double)means[h * 4096 + k];
    __syncthreads();
    const int t = (tc << 8) + tid;
    const float4* row = reinterpret_cast<const float4*>(qk + (((size_t)bh << 13) + t) * 64);
    double x[64];
#pragma unroll
    for (int k = 0; k < 16; ++k) {
        float4 f = row[k];
        x[4*k+0] = f.x; x[4*k+1] = f.y; x[4*k+2] = f.z; x[4*k+3] = f.w;
    }
    double n2 = 0.0;
#pragma unroll
    for (int d = 0; d < 64; ++d) n2 += x[d] * x[d];
    double den = sqrt(n2);
    den = den > 1e-12 ? den : 1e-12;
    const double rden = 1.0 / den;
    unsigned long long* dst = keys + ((size_t)bh << 19) + t;     // [bh][c][t]
    for (int c = 0; c < 64; ++c) {
        double a0 = 0.0, a1 = 0.0, a2 = 0.0, a3 = 0.0;
#pragma unroll
        for (int d = 0; d < 64; d += 4) {
            a0 += x[d+0] * ms[(c << 6) + d + 0];
            a1 += x[d+1] * ms[(c << 6) + d + 1];
            a2 += x[d+2] * ms[(c << 6) + d + 2];
            a3 += x[d+3] * ms[(c << 6) + d + 3];
        }
        const double val = ((a0 + a1) + (a2 + a3)) * rden;
        unsigned long long u = (unsigned long long)__double_as_longlong(val);
        u = (u & 0x8000000000000000ULL) ? ~u : (u | 0x8000000000000000ULL);
        dst[(size_t)c << 13] = u;
    }
}

// ---------------- Kernel B: exact top-128 per (b,h,c), ascending ----------------
__global__ __launch_bounds__(256) void topk_kernel(const unsigned long long* __restrict__ keys,
                                                   int* __restrict__ idx_out) {
    typedef unsigned long long KeyT;
    __shared__ KeyT key[8192];
    __shared__ unsigned hist[256];
    __shared__ unsigned sgt[256], seq[256];
    __shared__ KeyT s_prefix;
    __shared__ unsigned s_need;
    const int tid = threadIdx.x;
    const KeyT* col = keys + ((size_t)blockIdx.x << 13);
    for (int k = tid; k < 8192; k += 256) key[k] = col[k];
    __syncthreads();
    KeyT prefix = 0;
    unsigned need = 128u;
    for (int shift = 56; shift >= 0; shift -= 8) {
        hist[tid] = 0u;
        __syncthreads();
        const KeyT maskHi = (shift == 56) ? (KeyT)0 : (KeyT)((~(KeyT)0) << (shift + 8));
        for (int k = tid; k < 8192; k += 256) {
            KeyT u = key[k];
            if ((u & maskHi) == prefix) atomicAdd(&hist[(unsigned)(u >> shift) & 255u], 1u);
        }
        __syncthreads();
        // parallel suffix scan: hist[d] -> sum_{x>=d} hist[x]
        for (int off = 1; off < 256; off <<= 1) {
            unsigned add = (tid + off < 256) ? hist[tid + off] : 0u;
            __syncthreads();
            hist[tid] += add;
            __syncthreads();
        }
        unsigned sd = hist[tid];
        unsigned sd1 = (tid < 255) ? hist[tid + 1] : 0u;
        if (sd >= need && sd1 < need) {
            s_prefix = prefix | ((KeyT)(unsigned)tid << shift);
            s_need = need - sd1;
        }
        __syncthreads();
        prefix = s_prefix;
        need = s_need;
        __syncthreads();
    }
    const KeyT V = prefix;
    const unsigned rneed = need;
    const int base = tid << 5;
    unsigned cgt = 0, ceq = 0;
    for (int k = 0; k < 32; ++k) {
        KeyT u = key[base + k];
        cgt += (u > V) ? 1u : 0u;
        ceq += (u == V) ? 1u : 0u;
    }
    sgt[tid] = cgt; seq[tid] = ceq;
    __syncthreads();
    for (int off = 1; off < 256; off <<= 1) {
        unsigned ag = (tid >= off) ? sgt[tid - off] : 0u;
        unsigned ae = (tid >= off) ? seq[tid - off] : 0u;
        __syncthreads();
        sgt[tid] += ag; seq[tid] += ae;
        __syncthreads();
    }
    unsigned g = sgt[tid] - cgt;
    unsigned e = seq[tid] - ceq;
    int* out = idx_out + (blockIdx.x << 7);
    for (int k = 0; k < 32; ++k) {
        KeyT u = key[base + k];
        if (u > V) {
            out[g + (e < rneed ? e : rneed)] = base + k;
            ++g;
        } else if (u == V) {
            if (e < rneed) out[g + e] = base + k;
            ++e;
        }
    }
}

// ---------------- Kernel C: windowed MFMA attention + scatter ----------------
// LDS: SA = {qhi[128][72], qlo[128][72]} -> {vt_hi[64][136], vt_lo[64][136]}
//      SB = {w[128][72]} -> {g2[128][134]} -> {phi[128][72], plo[128][72]}
__global__ __launch_bounds__(256, 2) void attn_kernel(const float* __restrict__ qk,
                                                      const float* __restrict__ vv,
                                                      const float* __restrict__ relw,
                                                      const int* __restrict__ idx,
                                                      float* __restrict__ numer,
                                                      float* __restrict__ dcnt) {
    __shared__ __align__(16) unsigned short SA[18432];
    __shared__ __align__(16) unsigned short SB[18432];
    __shared__ float invn_s[128];
    __shared__ int idxs_s[128];

    const int tid = threadIdx.x;
    const int bh  = blockIdx.x >> 6;
    const int h   = bh & 7;
    const int wv = tid >> 6, l = tid & 63, g = l >> 4, ln = l & 15;
    const size_t base_bh = ((size_t)bh) << 13;
    const float scale = 0.125f;

    if (tid < 128) {
        int ix = idx[(blockIdx.x << 7) + tid];
        idxs_s[tid] = ix;
        atomicAdd(&dcnt[(bh << 13) + ix], 1.0f);
    }
    __syncthreads();

    // ---- P1: gather q -> qhi/qlo + invn; load rel weights -> SB ----
    {
        const int r = tid >> 1, half = tid & 1;
        const float4* qsrc = reinterpret_cast<const float4*>(
            qk + (base_bh + idxs_s[r]) * 64 + half * 32);
        float x[32]; float nrm = 0.f;
#pragma unroll
        for (int k4 = 0; k4 < 8; ++k4) {
            float4 f = qsrc[k4];
            x[4*k4+0]=f.x; x[4*k4+1]=f.y; x[4*k4+2]=f.z; x[4*k4+3]=f.w;
            nrm += f.x*f.x + f.y*f.y + f.z*f.z + f.w*f.w;
        }
        nrm += __shfl_xor(nrm, 1);
        if (!half) invn_s[r] = 1.0f / fmaxf(sqrtf(nrm), 1e-12f);
        unsigned short* qhi = SA;
        unsigned short* qlo = SA + 9216;
        const int rb = r * 72 + half * 32;
#pragma unroll
        for (int m = 0; m < 16; ++m) {
            unsigned short h0 = f2bf(x[2*m]), h1 = f2bf(x[2*m+1]);
            *(unsigned*)&qhi[rb + 2*m] = (unsigned)h0 | ((unsigned)h1 << 16);
            unsigned short l0 = f2bf(x[2*m] - bf2f(h0));
            unsigned short l1 = f2bf(x[2*m+1] - bf2f(h1));
            *(unsigned*)&qlo[rb + 2*m] = (unsigned)l0 | ((unsigned)l1 << 16);
        }
        float wx[32];
        const float4* wsrc = reinterpret_cast<const float4*>(
            relw + (size_t)(r*8 + h) * 64 + half * 32);
#pragma unroll
        for (int k4 = 0; k4 < 8; ++k4) {
            float4 f = wsrc[k4];
            wx[4*k4+0]=f.x; wx[4*k4+1]=f.y; wx[4*k4+2]=f.z; wx[4*k4+3]=f.w;
        }
#pragma unroll
        for (int m = 0; m < 16; ++m) {
            unsigned short w0 = f2bf(wx[2*m]), w1 = f2bf(wx[2*m+1]);
            *(unsigned*)&SB[rb + 2*m] = (unsigned)w0 | ((unsigned)w1 << 16);
        }
    }
    __syncthreads();

    // ---- P2: Gram (3-split) + rel MFMAs ----
    const unsigned short* qhi = SA;
    const unsigned short* qlo = SA + 9216;
    short8 aH[2][2], aL[2][2];
#pragma unroll
    for (int it = 0; it < 2; ++it)
#pragma unroll
        for (int kc = 0; kc < 2; ++kc) {
            int ro = (wv*32 + it*16 + ln) * 72 + kc*32 + g*8;
            aH[it][kc] = *(const short8*)&qhi[ro];
            aL[it][kc] = *(const short8*)&qlo[ro];
        }
    f32x4 accD[2][8], accG[2][8];
#pragma unroll
    for (int it = 0; it < 2; ++it)
#pragma unroll
        for (int jt = 0; jt < 8; ++jt) {
            accD[it][jt] = (f32x4)0.f;
            accG[it][jt] = (f32x4)0.f;
        }
#pragma unroll
    for (int jt = 0; jt < 8; ++jt) {
        const int rb = (jt*16 + ln) * 72 + g*8;
        short8 bH0 = *(const short8*)&qhi[rb];
        short8 bH1 = *(const short8*)&qhi[rb + 32];
        short8 bL0 = *(const short8*)&qlo[rb];
        short8 bL1 = *(const short8*)&qlo[rb + 32];
        short8 w0  = *(const short8*)&SB[rb];
        short8 w1  = *(const short8*)&SB[rb + 32];
#pragma unroll
        for (int it = 0; it < 2; ++it) {
            f32x4 d = accD[it][jt];
            d = __builtin_amdgcn_mfma_f32_16x16x32_bf16(aH[it][0], bH0, d, 0, 0, 0);
            d = __builtin_amdgcn_mfma_f32_16x16x32_bf16(aH[it][1], bH1, d, 0, 0, 0);
            d = __builtin_amdgcn_mfma_f32_16x16x32_bf16(aH[it][0], bL0, d, 0, 0, 0);
            d = __builtin_amdgcn_mfma_f32_16x16x32_bf16(aH[it][1], bL1, d, 0, 0, 0);
            d = __builtin_amdgcn_mfma_f32_16x16x32_bf16(aL[it][0], bH0, d, 0, 0, 0);
            d = __builtin_amdgcn_mfma_f32_16x16x32_bf16(aL[it][1], bH1, d, 0, 0, 0);
            accD[it][jt] = d;
            f32x4 gg = accG[it][jt];
            gg = __builtin_amdgcn_mfma_f32_16x16x32_bf16(aH[it][0], w0, gg, 0, 0, 0);
            gg = __builtin_amdgcn_mfma_f32_16x16x32_bf16(aH[it][1], w1, gg, 0, 0, 0);
            accG[it][jt] = gg;
        }
    }
    // ---- issue v gather (consumed after barrier) ----
    const int j0 = (tid & 63) * 2, dbase = (tid >> 6) * 16;
    const float4* vs0 = reinterpret_cast<const float4*>(vv + (base_bh + idxs_s[j0])   * 64 + dbase);
    const float4* vs1 = reinterpret_cast<const float4*>(vv + (base_bh + idxs_s[j0+1]) * 64 + dbase);
    float4 va[4], vb[4];
#pragma unroll
    for (int m = 0; m < 4; ++m) { va[m] = vs0[m]; vb[m] = vs1[m]; }
    __syncthreads();   // q, w dead; SA/SB reusable

    // ---- P3: write g2 (SB) and vt (SA) ----
#pragma unroll
    for (int it = 0; it < 2; ++it)
#pragma unroll
        for (int jt = 0; jt < 8; ++jt) {
            const int i0 = wv*32 + it*16 + g*4;
            const int c = jt*16 + ln;
#pragma unroll
            for (int r = 0; r < 4; ++r)
                SB[(i0 + r)*134 + c] = f2bf(accG[it][jt][r]);
        }
    {
        unsigned short* vth = SA;
        unsigned short* vtl = SA + 8704;
#pragma unroll
        for (int m = 0; m < 4; ++m) {
            float pa[4] = {va[m].x, va[m].y, va[m].z, va[m].w};
            float pb[4] = {vb[m].x, vb[m].y, vb[m].z, vb[m].w};
#pragma unroll
            for (int e = 0; e < 4; ++e) {
                const int d = dbase + 4*m + e;
                unsigned short h0 = f2bf(pa[e]), h1 = f2bf(pb[e]);
                *(unsigned*)&vth[d*136 + j0] = (unsigned)h0 | ((unsigned)h1 << 16);
                unsigned short l0 = f2bf(pa[e] - bf2f(h0));
                unsigned short l1 = f2bf(pb[e] - bf2f(h1));
                *(unsigned*)&vtl[d*136 + j0] = (unsigned)l0 | ((unsigned)l1 << 16);
            }
        }
    }
    __syncthreads();

    // ---- P4: epilogue logits + in-register softmax ----
    float invc[8];
#pragma unroll
    for (int jt = 0; jt < 8; ++jt) invc[jt] = invn_s[jt*16 + ln];
    float p[2][8][4];
#pragma unroll
    for (int it = 0; it < 2; ++it)
#pragma unroll
        for (int jt = 0; jt < 8; ++jt) {
            const int c = jt*16 + ln;
#pragma unroll
            for (int r = 0; r < 4; ++r) {
                const int i = wv*32 + it*16 + g*4 + r;
                float val = accD[it][jt][r] * (scale * invc[jt]);
                if (c <= i) val += scale * bf2f(SB[i*134 + (127 + c - i)]);
                if (c == i) val = TOKEN_SELF;
                p[it][jt][r] = val;
            }
        }
#pragma unroll
    for (int it = 0; it < 2; ++it)
#pragma unroll
        for (int r = 0; r < 4; ++r) {
            float m = p[it][0][r];
#pragma unroll
            for (int jt = 1; jt < 8; ++jt) m = fmaxf(m, p[it][jt][r]);
            m = fmaxf(m, __shfl_xor(m, 1));
            m = fmaxf(m, __shfl_xor(m, 2));
            m = fmaxf(m, __shfl_xor(m, 4));
            m = fmaxf(m, __shfl_xor(m, 8));
            float s = 0.f;
#pragma unroll
            for (int jt = 0; jt < 8; ++jt) {
                float e = __expf(p[it][jt][r] - m);
                p[it][jt][r] = e;
                s += e;
            }
            s += __shfl_xor(s, 1);
            s += __shfl_xor(s, 2);
            s += __shfl_xor(s, 4);
            s += __shfl_xor(s, 8);
            const float rs = 1.0f / s;
#pragma unroll
            for (int jt = 0; jt < 8; ++jt) p[it][jt][r] *= rs;
        }

    // ---- P5/P6: PV in two K-halves (P split hi/lo, V split hi/lo) ----
    f32x4 accO[2][4];
#pragma unroll
    for (int it = 0; it < 2; ++it)
#pragma unroll
        for (int nt = 0; nt < 4; ++nt) accO[it][nt] = (f32x4)0.f;
    unsigned short* phi = SB;
    unsigned short* plo = SB + 9216;
    const unsigned short* vthc = SA;
    const unsigned short* vtlc = SA + 8704;
#pragma unroll
    for (int kh = 0; kh < 2; ++kh) {
        __syncthreads();   // kh=0: g2 reads done; kh=1: prior A-frag reads done
#pragma unroll
        for (int it = 0; it < 2; ++it)
#pragma unroll
            for (int jtl = 0; jtl < 4; ++jtl) {
                const int jt = kh*4 + jtl;
#pragma unroll
                for (int r = 0; r < 4; ++r) {
                    const int i = wv*32 + it*16 + g*4 + r;
                    const int cs = (jtl*16 + ln) ^ (((i >> 2) & 3) << 3);
                    const float pv = p[it][jt][r];
                    const unsigned short hb = f2bf(pv);
                    phi[i*72 + cs] = hb;
                    plo[i*72 + cs] = f2bf(pv - bf2f(hb));
                }
            }
        __syncthreads();
#pragma unroll
        for (int kc = 0; kc < 2; ++kc) {
            short8 aPh[2], aPl[2];
#pragma unroll
            for (int it = 0; it < 2; ++it) {
                const int i = wv*32 + it*16 + ln;
                const int jb = (kc*32 + g*8) ^ (((ln >> 2) & 3) << 3);
                aPh[it] = *(const short8*)&phi[i*72 + jb];
                aPl[it] = *(const short8*)&plo[i*72 + jb];
            }
#pragma unroll
            for (int nt = 0; nt < 4; ++nt) {
                const int vo = (nt*16 + ln)*136 + kh*64 + kc*32 + g*8;
                short8 bh_ = *(const short8*)&vthc[vo];
                short8 bl_ = *(const short8*)&vtlc[vo];
#pragma unroll
                for (int it = 0; it < 2; ++it) {
                    f32x4 o = accO[it][nt];
                    o = __builtin_amdgcn_mfma_f32_16x16x32_bf16(aPh[it], bh_, o, 0, 0, 0);
                    o = __builtin_amdgcn_mfma_f32_16x16x32_bf16(aPh[it], bl_, o, 0, 0, 0);
                    o = __builtin_amdgcn_mfma_f32_16x16x32_bf16(aPl[it], bh_, o, 0, 0, 0);
                    accO[it][nt] = o;
                }
            }
        }
    }

    // ---- P7: scatter ----
#pragma unroll
    for (int it = 0; it < 2; ++it)
#pragma unroll
        for (int nt = 0; nt < 4; ++nt)
#pragma unroll
            for (int r = 0; r < 4; ++r) {
                const int i = wv*32 + it*16 + g*4 + r;
                const int tok = idxs_s[i];
                const int d = nt*16 + ln;
                atomicAdd(&numer[(base_bh + tok)*64 + d], accO[it][nt][r]);
            }
}

// ---------------- Kernel D: finalize ----------------
__global__ __launch_bounds__(256) void finalize_kernel(float4* __restrict__ out,
                                                       const float* __restrict__ dcnt) {
    const int i = blockIdx.x * 256 + threadIdx.x;   // [0, 2097152)
    const float dnm = dcnt[i >> 4] + 1e-5f;
    float4 o = out[i];
    o.x /= dnm; o.y /= dnm; o.z /= dnm; o.w /= dnm;
    out[i] = o;
}

extern "C" void kernel_launch(void* const* d_in, const int* in_sizes, int n_in,
                              void* d_out, int out_size, void* d_ws, size_t ws_size,
                              hipStream_t stream) {
    const float* qk    = (const float*)d_in[0];
    const float* vv    = (const float*)d_in[1];
    const float* means = (const float*)d_in[2];
    const float* relw  = (const float*)d_in[3];
    float* out = (float*)d_out;

    const size_t nkeys     = (size_t)16 * 64 * 8192;   // 8,388,608 keys
    const size_t idx_bytes = (size_t)1024 * 128 * 4;   // 524,288
    const size_t cnt_bytes = (size_t)16 * 8192 * 4;    // 524,288
    char* wsb = (char*)d_ws;
    const size_t keyBytes = nkeys * 8;
    int* idxp   = (int*)(wsb + keyBytes);
    float* dcnt = (float*)(wsb + keyBytes + idx_bytes);

    hipMemsetAsync(d_out, 0, (size_t)out_size * 4, stream);
    hipMemsetAsync(dcnt, 0, cnt_bytes, stream);

    dists_kernel<<<512, 256, 0, stream>>>(qk, means, (unsigned long long*)wsb);
    topk_kernel<<<1024, 256, 0, stream>>>((const unsigned long long*)wsb, idxp);
    attn_kernel<<<1024, 256, 0, stream>>>(qk, vv, relw, idxp, out, dcnt);
    finalize_kernel<<<8192, 256, 0, stream>>>((float4*)d_out, dcnt);
}

// Round 3
// 162.795 us; speedup vs baseline: 6.2515x; 1.4320x over previous
//
#include <hip/hip_runtime.h>

// KmeansAttention: b=2 h=8 t=8192 d=64 c=64 wsz=128
// A) routing dists (f64 accumulate, exact ranking) -> monotone u32 keys
// B) per-(b,h,c) 4-pass radix-select top-128 tokens, ascending indices
// C) per-window 128x128 MFMA attention (split-bf16 Gram + rel-shift + softmax
//    + split-bf16 PV), atomic scatter into numer(d_out) + count
// D) out = numer / (count + 1e-5)

#define TOKEN_SELF -50000.0f

typedef __attribute__((ext_vector_type(8))) short short8;
typedef __attribute__((ext_vector_type(4))) float f32x4;

__device__ __forceinline__ unsigned short f2bf(float x) {
    unsigned u = __float_as_uint(x);
    u += 0x7fffu + ((u >> 16) & 1u);
    return (unsigned short)(u >> 16);
}
__device__ __forceinline__ float bf2f(unsigned short b) {
    return __uint_as_float(((unsigned)b) << 16);
}

// ---------------- Kernel A: routing distances -> sortable u32 keys ----------------
__global__ __launch_bounds__(256) void dists_kernel(const float* __restrict__ qk,
                                                    const float* __restrict__ means,
                                                    unsigned* __restrict__ keys) {
    __shared__ double ms[4096];              // means[h] as f64, 32KB
    const int tid = threadIdx.x;
    const int bh = blockIdx.x >> 5;          // [0,16)
    const int tc = blockIdx.x & 31;          // token chunk of 256
    const int h = bh & 7;
    for (int k = tid; k < 4096; k += 256) ms[k] = (double)means[h * 4096 + k];
    __syncthreads();
    const int t = (tc << 8) + tid;
    const float4* row = reinterpret_cast<const float4*>(qk + (((size_t)bh << 13) + t) * 64);
    double x[64];
#pragma unroll
    for (int k = 0; k < 16; ++k) {
        float4 f = row[k];
        x[4*k+0] = f.x; x[4*k+1] = f.y; x[4*k+2] = f.z; x[4*k+3] = f.w;
    }
    double n2 = 0.0;
#pragma unroll
    for (int d = 0; d < 64; ++d) n2 += x[d] * x[d];
    double den = sqrt(n2);
    den = den > 1e-12 ? den : 1e-12;
    const double rden = 1.0 / den;
    unsigned* dst = keys + ((size_t)bh << 19) + t;     // [bh][c][t]
    for (int c = 0; c < 64; ++c) {
        double a0 = 0.0, a1 = 0.0, a2 = 0.0, a3 = 0.0;
#pragma unroll
        for (int d = 0; d < 64; d += 4) {
            a0 += x[d+0] * ms[(c << 6) + d + 0];
            a1 += x[d+1] * ms[(c << 6) + d + 1];
            a2 += x[d+2] * ms[(c << 6) + d + 2];
            a3 += x[d+3] * ms[(c << 6) + d + 3];
        }
        const double val = ((a0 + a1) + (a2 + a3)) * rden;   // in [-1,1]
        // monotone map to u32, granularity 5e-10 (reference f32 noise ~1e-7)
        const long long q = __double2ll_rn(val * 2.0e9);
        dst[(size_t)c << 13] = (unsigned)(q + 2147483648LL);
    }
}

// ---------------- Kernel B: exact top-128 per (b,h,c), ascending ----------------
__global__ __launch_bounds__(256) void topk_kernel(const unsigned* __restrict__ keys,
                                                   int* __restrict__ idx_out) {
    __shared__ __align__(16) unsigned key[8192];   // 32KB
    __shared__ unsigned hist[256];
    __shared__ unsigned s_prefix, s_need;
    __shared__ unsigned wg[4], we[4];
    const int tid = threadIdx.x;
    const int lane = tid & 63;
    const int w = tid >> 6;

    {
        const uint4* src4 = reinterpret_cast<const uint4*>(keys + ((size_t)blockIdx.x << 13));
        uint4* k4 = reinterpret_cast<uint4*>(key);
        for (int k = tid; k < 2048; k += 256) k4[k] = src4[k];
    }
    __syncthreads();

    unsigned prefix = 0, need = 128u;
#pragma unroll
    for (int shift = 24; shift >= 0; shift -= 8) {
        hist[tid] = 0u;
        __syncthreads();
        const unsigned maskHi = (shift == 24) ? 0u : (0xFFFFFFFFu << (shift + 8));
        for (int k = tid; k < 8192; k += 256) {
            unsigned u = key[k];
            if ((u & maskHi) == prefix) atomicAdd(&hist[(u >> shift) & 255u], 1u);
        }
        __syncthreads();
        // suffix sums over 256 bins by wave 0 (4 bins/lane, shfl suffix scan)
        if (tid < 64) {
            unsigned h0 = hist[tid*4], h1 = hist[tid*4+1], h2 = hist[tid*4+2], h3 = hist[tid*4+3];
            unsigned tot = h0 + h1 + h2 + h3;
            unsigned s = tot;
#pragma unroll
            for (int off = 1; off < 64; off <<= 1) {
                unsigned tdown = __shfl_down(s, off);
                if (tid + off < 64) s += tdown;
            }
            const unsigned above = s - tot;    // sum over lanes > tid
            hist[tid*4+3] = above + h3;
            hist[tid*4+2] = above + h3 + h2;
            hist[tid*4+1] = above + h3 + h2 + h1;
            hist[tid*4+0] = above + tot;
        }
        __syncthreads();
        // digit selection: hist[d] = count of keys >= digit d (within prefix)
        {
            const unsigned sd = hist[tid];
            const unsigned sd1 = (tid < 255) ? hist[tid + 1] : 0u;
            if (sd >= need && sd1 < need) {
                s_prefix = prefix | ((unsigned)tid << shift);
                s_need = need - sd1;
            }
        }
        __syncthreads();
        prefix = s_prefix;
        need = s_need;
    }

    const unsigned V = prefix;       // exact 128th key value
    const unsigned rneed = need;     // how many ==V to include (smallest indices)
    const int base = tid << 5;
    unsigned cgt = 0, ceq = 0;
#pragma unroll 8
    for (int k = 0; k < 32; ++k) {
        unsigned u = key[base + k];
        cgt += (u > V) ? 1u : 0u;
        ceq += (u == V) ? 1u : 0u;
    }
    // block exclusive scan of (cgt, ceq) via wave shfl + wave totals
    unsigned gi = cgt, ei = ceq;
#pragma unroll
    for (int off = 1; off < 64; off <<= 1) {
        unsigned tg = __shfl_up(gi, off);
        unsigned te = __shfl_up(ei, off);
        if (lane >= off) { gi += tg; ei += te; }
    }
    if (lane == 63) { wg[w] = gi; we[w] = ei; }
    __syncthreads();
    unsigned og = 0, oe = 0;
    for (int x = 0; x < w; ++x) { og += wg[x]; oe += we[x]; }
    unsigned g = og + gi - cgt;
    unsigned e = oe + ei - ceq;
    int* out = idx_out + (blockIdx.x << 7);
    for (int k = 0; k < 32; ++k) {
        unsigned u = key[base + k];
        if (u > V) {
            out[g + (e < rneed ? e : rneed)] = base + k;
            ++g;
        } else if (u == V) {
            if (e < rneed) out[g + e] = base + k;
            ++e;
        }
    }
}

// ---------------- Kernel C: windowed MFMA attention + scatter ----------------
// LDS: SA = {qhi[128][72], qlo[128][72]} -> {vt_hi[64][136], vt_lo[64][136]}
//      SB = {w[128][72]} -> {g2[128][134]} -> {phi[128][72], plo[128][72]}
__global__ __launch_bounds__(256, 2) void attn_kernel(const float* __restrict__ qk,
                                                      const float* __restrict__ vv,
                                                      const float* __restrict__ relw,
                                                      const int* __restrict__ idx,
                                                      float* __restrict__ numer,
                                                      float* __restrict__ dcnt) {
    __shared__ __align__(16) unsigned short SA[18432];
    __shared__ __align__(16) unsigned short SB[18432];
    __shared__ float invn_s[128];
    __shared__ int idxs_s[128];

    const int tid = threadIdx.x;
    const int bh  = blockIdx.x >> 6;
    const int h   = bh & 7;
    const int wv = tid >> 6, l = tid & 63, g = l >> 4, ln = l & 15;
    const size_t base_bh = ((size_t)bh) << 13;
    const float scale = 0.125f;

    if (tid < 128) {
        int ix = idx[(blockIdx.x << 7) + tid];
        idxs_s[tid] = ix;
        atomicAdd(&dcnt[(bh << 13) + ix], 1.0f);
    }
    __syncthreads();

    // ---- P1: gather q -> qhi/qlo + invn; load rel weights -> SB ----
    {
        const int r = tid >> 1, half = tid & 1;
        const float4* qsrc = reinterpret_cast<const float4*>(
            qk + (base_bh + idxs_s[r]) * 64 + half * 32);
        float x[32]; float nrm = 0.f;
#pragma unroll
        for (int k4 = 0; k4 < 8; ++k4) {
            float4 f = qsrc[k4];
            x[4*k4+0]=f.x; x[4*k4+1]=f.y; x[4*k4+2]=f.z; x[4*k4+3]=f.w;
            nrm += f.x*f.x + f.y*f.y + f.z*f.z + f.w*f.w;
        }
        nrm += __shfl_xor(nrm, 1);
        if (!half) invn_s[r] = 1.0f / fmaxf(sqrtf(nrm), 1e-12f);
        unsigned short* qhi = SA;
        unsigned short* qlo = SA + 9216;
        const int rb = r * 72 + half * 32;
#pragma unroll
        for (int m = 0; m < 16; ++m) {
            unsigned short h0 = f2bf(x[2*m]), h1 = f2bf(x[2*m+1]);
            *(unsigned*)&qhi[rb + 2*m] = (unsigned)h0 | ((unsigned)h1 << 16);
            unsigned short l0 = f2bf(x[2*m] - bf2f(h0));
            unsigned short l1 = f2bf(x[2*m+1] - bf2f(h1));
            *(unsigned*)&qlo[rb + 2*m] = (unsigned)l0 | ((unsigned)l1 << 16);
        }
        float wx[32];
        const float4* wsrc = reinterpret_cast<const float4*>(
            relw + (size_t)(r*8 + h) * 64 + half * 32);
#pragma unroll
        for (int k4 = 0; k4 < 8; ++k4) {
            float4 f = wsrc[k4];
            wx[4*k4+0]=f.x; wx[4*k4+1]=f.y; wx[4*k4+2]=f.z; wx[4*k4+3]=f.w;
        }
#pragma unroll
        for (int m = 0; m < 16; ++m) {
            unsigned short w0 = f2bf(wx[2*m]), w1 = f2bf(wx[2*m+1]);
            *(unsigned*)&SB[rb + 2*m] = (unsigned)w0 | ((unsigned)w1 << 16);
        }
    }
    __syncthreads();

    // ---- P2: Gram (3-split) + rel MFMAs ----
    const unsigned short* qhi = SA;
    const unsigned short* qlo = SA + 9216;
    short8 aH[2][2], aL[2][2];
#pragma unroll
    for (int it = 0; it < 2; ++it)
#pragma unroll
        for (int kc = 0; kc < 2; ++kc) {
            int ro = (wv*32 + it*16 + ln) * 72 + kc*32 + g*8;
            aH[it][kc] = *(const short8*)&qhi[ro];
            aL[it][kc] = *(const short8*)&qlo[ro];
        }
    f32x4 accD[2][8], accG[2][8];
#pragma unroll
    for (int it = 0; it < 2; ++it)
#pragma unroll
        for (int jt = 0; jt < 8; ++jt) {
            accD[it][jt] = (f32x4)0.f;
            accG[it][jt] = (f32x4)0.f;
        }
#pragma unroll
    for (int jt = 0; jt < 8; ++jt) {
        const int rb = (jt*16 + ln) * 72 + g*8;
        short8 bH0 = *(const short8*)&qhi[rb];
        short8 bH1 = *(const short8*)&qhi[rb + 32];
        short8 bL0 = *(const short8*)&qlo[rb];
        short8 bL1 = *(const short8*)&qlo[rb + 32];
        short8 w0  = *(const short8*)&SB[rb];
        short8 w1  = *(const short8*)&SB[rb + 32];
#pragma unroll
        for (int it = 0; it < 2; ++it) {
            f32x4 d = accD[it][jt];
            d = __builtin_amdgcn_mfma_f32_16x16x32_bf16(aH[it][0], bH0, d, 0, 0, 0);
            d = __builtin_amdgcn_mfma_f32_16x16x32_bf16(aH[it][1], bH1, d, 0, 0, 0);
            d = __builtin_amdgcn_mfma_f32_16x16x32_bf16(aH[it][0], bL0, d, 0, 0, 0);
            d = __builtin_amdgcn_mfma_f32_16x16x32_bf16(aH[it][1], bL1, d, 0, 0, 0);
            d = __builtin_amdgcn_mfma_f32_16x16x32_bf16(aL[it][0], bH0, d, 0, 0, 0);
            d = __builtin_amdgcn_mfma_f32_16x16x32_bf16(aL[it][1], bH1, d, 0, 0, 0);
            accD[it][jt] = d;
            f32x4 gg = accG[it][jt];
            gg = __builtin_amdgcn_mfma_f32_16x16x32_bf16(aH[it][0], w0, gg, 0, 0, 0);
            gg = __builtin_amdgcn_mfma_f32_16x16x32_bf16(aH[it][1], w1, gg, 0, 0, 0);
            accG[it][jt] = gg;
        }
    }
    // ---- issue v gather (consumed after barrier) ----
    const int j0 = (tid & 63) * 2, dbase = (tid >> 6) * 16;
    const float4* vs0 = reinterpret_cast<const float4*>(vv + (base_bh + idxs_s[j0])   * 64 + dbase);
    const float4* vs1 = reinterpret_cast<const float4*>(vv + (base_bh + idxs_s[j0+1]) * 64 + dbase);
    float4 va[4], vb[4];
#pragma unroll
    for (int m = 0; m < 4; ++m) { va[m] = vs0[m]; vb[m] = vs1[m]; }
    __syncthreads();   // q, w dead; SA/SB reusable

    // ---- P3: write g2 (SB) and vt (SA) ----
#pragma unroll
    for (int it = 0; it < 2; ++it)
#pragma unroll
        for (int jt = 0; jt < 8; ++jt) {
            const int i0 = wv*32 + it*16 + g*4;
            const int c = jt*16 + ln;
#pragma unroll
            for (int r = 0; r < 4; ++r)
                SB[(i0 + r)*134 + c] = f2bf(accG[it][jt][r]);
        }
    {
        unsigned short* vth = SA;
        unsigned short* vtl = SA + 8704;
#pragma unroll
        for (int m = 0; m < 4; ++m) {
            float pa[4] = {va[m].x, va[m].y, va[m].z, va[m].w};
            float pb[4] = {vb[m].x, vb[m].y, vb[m].z, vb[m].w};
#pragma unroll
            for (int e = 0; e < 4; ++e) {
                const int d = dbase + 4*m + e;
                unsigned short h0 = f2bf(pa[e]), h1 = f2bf(pb[e]);
                *(unsigned*)&vth[d*136 + j0] = (unsigned)h0 | ((unsigned)h1 << 16);
                unsigned short l0 = f2bf(pa[e] - bf2f(h0));
                unsigned short l1 = f2bf(pb[e] - bf2f(h1));
                *(unsigned*)&vtl[d*136 + j0] = (unsigned)l0 | ((unsigned)l1 << 16);
            }
        }
    }
    __syncthreads();

    // ---- P4: epilogue logits + in-register softmax ----
    float invc[8];
#pragma unroll
    for (int jt = 0; jt < 8; ++jt) invc[jt] = invn_s[jt*16 + ln];
    float p[2][8][4];
#pragma unroll
    for (int it = 0; it < 2; ++it)
#pragma unroll
        for (int jt = 0; jt < 8; ++jt) {
            const int c = jt*16 + ln;
#pragma unroll
            for (int r = 0; r < 4; ++r) {
                const int i = wv*32 + it*16 + g*4 + r;
                float val = accD[it][jt][r] * (scale * invc[jt]);
                if (c <= i) val += scale * bf2f(SB[i*134 + (127 + c - i)]);
                if (c == i) val = TOKEN_SELF;
                p[it][jt][r] = val;
            }
        }
#pragma unroll
    for (int it = 0; it < 2; ++it)
#pragma unroll
        for (int r = 0; r < 4; ++r) {
            float m = p[it][0][r];
#pragma unroll
            for (int jt = 1; jt < 8; ++jt) m = fmaxf(m, p[it][jt][r]);
            m = fmaxf(m, __shfl_xor(m, 1));
            m = fmaxf(m, __shfl_xor(m, 2));
            m = fmaxf(m, __shfl_xor(m, 4));
            m = fmaxf(m, __shfl_xor(m, 8));
            float s = 0.f;
#pragma unroll
            for (int jt = 0; jt < 8; ++jt) {
                float e = __expf(p[it][jt][r] - m);
                p[it][jt][r] = e;
                s += e;
            }
            s += __shfl_xor(s, 1);
            s += __shfl_xor(s, 2);
            s += __shfl_xor(s, 4);
            s += __shfl_xor(s, 8);
            const float rs = 1.0f / s;
#pragma unroll
            for (int jt = 0; jt < 8; ++jt) p[it][jt][r] *= rs;
        }

    // ---- P5/P6: PV in two K-halves (P split hi/lo, V split hi/lo) ----
    f32x4 accO[2][4];
#pragma unroll
    for (int it = 0; it < 2; ++it)
#pragma unroll
        for (int nt = 0; nt < 4; ++nt) accO[it][nt] = (f32x4)0.f;
    unsigned short* phi = SB;
    unsigned short* plo = SB + 9216;
    const unsigned short* vthc = SA;
    const unsigned short* vtlc = SA + 8704;
#pragma unroll
    for (int kh = 0; kh < 2; ++kh) {
        __syncthreads();   // kh=0: g2 reads done; kh=1: prior A-frag reads done
#pragma unroll
        for (int it = 0; it < 2; ++it)
#pragma unroll
            for (int jtl = 0; jtl < 4; ++jtl) {
                const int jt = kh*4 + jtl;
#pragma unroll
                for (int r = 0; r < 4; ++r) {
                    const int i = wv*32 + it*16 + g*4 + r;
                    const int cs = (jtl*16 + ln) ^ (((i >> 2) & 3) << 3);
                    const float pv = p[it][jt][r];
                    const unsigned short hb = f2bf(pv);
                    phi[i*72 + cs] = hb;
                    plo[i*72 + cs] = f2bf(pv - bf2f(hb));
                }
            }
        __syncthreads();
#pragma unroll
        for (int kc = 0; kc < 2; ++kc) {
            short8 aPh[2], aPl[2];
#pragma unroll
            for (int it = 0; it < 2; ++it) {
                const int i = wv*32 + it*16 + ln;
                const int jb = (kc*32 + g*8) ^ (((ln >> 2) & 3) << 3);
                aPh[it] = *(const short8*)&phi[i*72 + jb];
                aPl[it] = *(const short8*)&plo[i*72 + jb];
            }
#pragma unroll
            for (int nt = 0; nt < 4; ++nt) {
                const int vo = (nt*16 + ln)*136 + kh*64 + kc*32 + g*8;
                short8 bh_ = *(const short8*)&vthc[vo];
                short8 bl_ = *(const short8*)&vtlc[vo];
#pragma unroll
                for (int it = 0; it < 2; ++it) {
                    f32x4 o = accO[it][nt];
                    o = __builtin_amdgcn_mfma_f32_16x16x32_bf16(aPh[it], bh_, o, 0, 0, 0);
                    o = __builtin_amdgcn_mfma_f32_16x16x32_bf16(aPh[it], bl_, o, 0, 0, 0);
                    o = __builtin_amdgcn_mfma_f32_16x16x32_bf16(aPl[it], bh_, o, 0, 0, 0);
                    accO[it][nt] = o;
                }
            }
        }
    }

    // ---- P7: scatter ----
#pragma unroll
    for (int it = 0; it < 2; ++it)
#pragma unroll
        for (int nt = 0; nt < 4; ++nt)
#pragma unroll
            for (int r = 0; r < 4; ++r) {
                const int i = wv*32 + it*16 + g*4 + r;
                const int tok = idxs_s[i];
                const int d = nt*16 + ln;
                atomicAdd(&numer[(base_bh + tok)*64 + d], accO[it][nt][r]);
            }
}

// ---------------- Kernel D: finalize ----------------
__global__ __launch_bounds__(256) void finalize_kernel(float4* __restrict__ out,
                                                       const float* __restrict__ dcnt) {
    const int i = blockIdx.x * 256 + threadIdx.x;   // [0, 2097152)
    const float dnm = dcnt[i >> 4] + 1e-5f;
    float4 o = out[i];
    o.x /= dnm; o.y /= dnm; o.z /= dnm; o.w /= dnm;
    out[i] = o;
}

extern "C" void kernel_launch(void* const* d_in, const int* in_sizes, int n_in,
                              void* d_out, int out_size, void* d_ws, size_t ws_size,
                              hipStream_t stream) {
    const float* qk    = (const float*)d_in[0];
    const float* vv    = (const float*)d_in[1];
    const float* means = (const float*)d_in[2];
    const float* relw  = (const float*)d_in[3];
    float* out = (float*)d_out;

    const size_t nkeys     = (size_t)16 * 64 * 8192;   // 8,388,608 keys (u32)
    const size_t idx_bytes = (size_t)1024 * 128 * 4;   // 524,288
    const size_t cnt_bytes = (size_t)16 * 8192 * 4;    // 524,288
    char* wsb = (char*)d_ws;
    const size_t keyBytes = nkeys * 4;
    int* idxp   = (int*)(wsb + keyBytes);
    float* dcnt = (float*)(wsb + keyBytes + idx_bytes);

    hipMemsetAsync(d_out, 0, (size_t)out_size * 4, stream);
    hipMemsetAsync(dcnt, 0, cnt_bytes, stream);

    dists_kernel<<<512, 256, 0, stream>>>(qk, means, (unsigned*)wsb);
    topk_kernel<<<1024, 256, 0, stream>>>((const unsigned*)wsb, idxp);
    attn_kernel<<<1024, 256, 0, stream>>>(qk, vv, relw, idxp, out, dcnt);
    finalize_kernel<<<8192, 256, 0, stream>>>((float4*)d_out, dcnt);
}